// Round 3
// baseline (192.865 us; speedup 1.0000x reference)
//
#include <hip/hip_runtime.h>
#include <hip/hip_bf16.h>
#include <math.h>

// ---------------- problem constants ----------------
#define SEQL 1024
#define DIMC 256
#define NBATCH 8
#define NTOK 256
#define NST 16

typedef unsigned short ushortT;
typedef unsigned int uintT;
using bf16x8 = __attribute__((ext_vector_type(8))) short;
using f32x4  = __attribute__((ext_vector_type(4))) float;

// ---------------- ws layout (float offsets) ----------------
static const size_t OFF_UF     = 0;            // 2097152 f32
static const size_t OFF_UB     = 2097152;      // 2097152
static const size_t OFF_DF     = 4194304;      // 2097152
static const size_t OFF_DB     = 6291456;      // 2097152
static const size_t OFF_BFa    = 8388608;      // 131072
static const size_t OFF_CFa    = 8519680;      // 131072
static const size_t OFF_BBa    = 8650752;      // 131072
static const size_t OFF_CBa    = 8781824;      // 131072
static const size_t OFF_POOLX  = 8912896;      // 524288
static const size_t OFF_ZP     = 9437184;      // 524288
static const size_t OFF_Y1P    = 9961472;      // 524288
static const size_t OFF_Y2P    = 10485760;     // 524288
static const size_t OFF_BFB    = 11010048;     // 256
static const size_t OFF_BBB    = 11010304;     // 256
static const size_t OFF_MASK   = 11010560;     // 256
static const size_t OFF_HOUT   = 11010816;     // 1048576
static const size_t OFF_PPROD  = 12059392;     // 1048576
static const size_t OFF_HIN    = 13107968;     // 1048576
// packed bf16 regions (sizes in floats; 2 ushorts per float slot)
static const size_t OFF_APK    = 14156544;     // 8192*256 bf16 = 1048576 f32 slots
static const size_t OFF_PPK    = 15205120;     // 2048*256 bf16 = 262144
static const size_t OFF_WFPK   = 15467264;     // 32768
static const size_t OFF_WBPK   = 15500032;     // 32768
static const size_t OFF_P1PK   = 15532800;     // 32768
// new: row-major bf16 weights for delta / BC GEMMs
static const size_t OFF_WD_F   = 15565568;     // 256*256 bf16 = 32768 f32 slots
static const size_t OFF_WD_B   = 15598336;     // 32768
static const size_t OFF_WBC_F  = 15631104;     // 32*256 bf16 = 4096
static const size_t OFF_WBC_B  = 15635200;     // 4096
// total 15639296 floats = ~62.6 MB

__device__ __forceinline__ float softplus_f(float x) {
    return fmaxf(x, 0.0f) + log1pf(__expf(-fabsf(x)));
}
__device__ __forceinline__ float silu_f(float x) {
    return x / (1.0f + __expf(-x));
}
__device__ __forceinline__ ushortT f2bf(float f) {
    uintT u = __float_as_uint(f);
    uintT r = (u + 0x7FFFu + ((u >> 16) & 1u)) >> 16;
    return (ushortT)r;
}
// fragment-pack index for element (k, n): layout [n16][kk][lane][j],
// lane = g*16 + (n&15), k = kk*32 + g*8 + j
__device__ __forceinline__ size_t pk_idx(int k, int n) {
    int n16 = n >> 4, kk = k >> 5, g = (k >> 3) & 3, j = k & 7;
    return ((((size_t)n16 * 8 + kk) * 64) + g * 16 + (n & 15)) * 8 + j;
}
__device__ __forceinline__ bf16x8 cvt8(float4 a, float4 b) {
    union { bf16x8 v; __hip_bfloat16 h[8]; } u8;
    u8.h[0] = __float2bfloat16(a.x); u8.h[1] = __float2bfloat16(a.y);
    u8.h[2] = __float2bfloat16(a.z); u8.h[3] = __float2bfloat16(a.w);
    u8.h[4] = __float2bfloat16(b.x); u8.h[5] = __float2bfloat16(b.y);
    u8.h[6] = __float2bfloat16(b.z); u8.h[7] = __float2bfloat16(b.w);
    return u8.v;
}

// ---------------- prep: combined conv∘p2 weights, packed bf16 ----------------
__global__ __launch_bounds__(256) void combine_w_k(
    const float* __restrict__ cf_w, const float* __restrict__ cf_b,
    const float* __restrict__ cb_w, const float* __restrict__ cb_b,
    const float* __restrict__ p2w, const float* __restrict__ p2b,
    ushortT* __restrict__ Wfpk, float* __restrict__ bf,
    ushortT* __restrict__ Wbpk, float* __restrict__ bb)
{
    int dir = blockIdx.y;
    const float* CW = dir ? cb_w : cf_w;
    const float* CB = dir ? cb_b : cf_b;
    ushortT* WPK = dir ? Wbpk : Wfpk;
    float* BO = dir ? bb : bf;
    int c = blockIdx.x;            // output channel -> GEMM col n
    int tid = threadIdx.x;         // input channel  -> GEMM k
    __shared__ float row[256];
    __shared__ float red[256];
    row[tid] = CW[c * 256 + tid];
    __syncthreads();
    float acc = 0.0f;
    for (int j = 0; j < 256; j++) acc += row[j] * p2w[j * 256 + tid];
    WPK[pk_idx(tid, c)] = f2bf(acc);
    red[tid] = row[tid] * p2b[tid];
    __syncthreads();
    for (int s = 128; s > 0; s >>= 1) {
        if (tid < s) red[tid] += red[tid + s];
        __syncthreads();
    }
    if (tid == 0) BO[c] = red[0] + CB[c];
}

__global__ __launch_bounds__(256) void pack_p1_k(const float* __restrict__ p1w,
                                                 ushortT* __restrict__ P1pk)
{
    int c = blockIdx.x, i = threadIdx.x;   // n = c, k = i
    P1pk[pk_idx(i, c)] = f2bf(p1w[c * 256 + i]);
}

// Wd[d][k] = sum_r dt_w[d][r] * dbc_w[r][k]  (row-major bf16, 256x256)
// Wbc[rr][k] = dbc_w[16+rr][k]               (row-major bf16, 32x256)
__global__ __launch_bounds__(256) void wd_prep_k(
    const float* __restrict__ dbcw_f, const float* __restrict__ dtw_f,
    const float* __restrict__ dbcw_b, const float* __restrict__ dtw_b,
    ushortT* __restrict__ Wd_f, ushortT* __restrict__ Wbc_f,
    ushortT* __restrict__ Wd_b, ushortT* __restrict__ Wbc_b)
{
    int dir = blockIdx.y;
    const float* DW = dir ? dbcw_b : dbcw_f;
    const float* TW = dir ? dtw_b : dtw_f;
    int xr = blockIdx.x, k = threadIdx.x;
    if (xr < 256) {
        float acc = 0.0f;
        #pragma unroll
        for (int r = 0; r < 16; r++) acc += TW[xr * 16 + r] * DW[r * 256 + k];
        (dir ? Wd_b : Wd_f)[xr * 256 + k] = f2bf(acc);
    } else {
        int rr = xr - 256;   // 0..31
        (dir ? Wbc_b : Wbc_f)[rr * 256 + k] = f2bf(DW[(16 + rr) * 256 + k]);
    }
}

__global__ __launch_bounds__(256) void mask_k(float* __restrict__ mask)
{
    int t = threadIdx.x;
    float dx = (float)t - 128.0f;
    float wv = __expf(-0.5f * dx * dx / 4096.0f);   // sigma = 64 exactly
    __shared__ float red[256];
    red[t] = wv;
    __syncthreads();
    for (int s = 128; s > 0; s >>= 1) {
        if (t < s) red[t] += red[t + s];
        __syncthreads();
    }
    mask[t] = wv / red[0];
}

// ---------------- LayerNorm + adapool(x) + packed xn / packed pool(xn) ----------------
__global__ __launch_bounds__(256) void ln_pool_k(
    const float* __restrict__ x, const float* __restrict__ g, const float* __restrict__ be,
    ushortT* __restrict__ Apk, float* __restrict__ poolx, ushortT* __restrict__ Ppk)
{
    int blk = blockIdx.x;           // b*256 + t
    int tid = threadIdx.x;
    int w = tid >> 6, lane = tid & 63;
    __shared__ float bufx[4][256];
    __shared__ float bufn[4][256];
    int row = blk * 4 + w;          // = b*1024 + 4t + w
    float4 v = *(const float4*)&x[(size_t)row * 256 + lane * 4];
    float s = v.x + v.y + v.z + v.w;
    #pragma unroll
    for (int m = 1; m < 64; m <<= 1) s += __shfl_xor(s, m);
    float mu = s * (1.0f / 256.0f);
    float cx = v.x - mu, cy = v.y - mu, cz = v.z - mu, cw = v.w - mu;
    float ss = cx * cx + cy * cy + cz * cz + cw * cw;
    #pragma unroll
    for (int m = 1; m < 64; m <<= 1) ss += __shfl_xor(ss, m);
    float rs = rsqrtf(ss * (1.0f / 256.0f) + 1e-5f);
    float4 g4 = *(const float4*)&g[lane * 4];
    float4 b4 = *(const float4*)&be[lane * 4];
    float4 o;
    o.x = cx * rs * g4.x + b4.x;
    o.y = cy * rs * g4.y + b4.y;
    o.z = cz * rs * g4.z + b4.z;
    o.w = cw * rs * g4.w + b4.w;
    {
        int c0 = lane * 4;
        size_t pidx = pk_idx(c0, row);
        ushort4 pv;
        pv.x = f2bf(o.x); pv.y = f2bf(o.y); pv.z = f2bf(o.z); pv.w = f2bf(o.w);
        *(ushort4*)&Apk[pidx] = pv;
    }
    *(float4*)&bufx[w][lane * 4] = v;
    *(float4*)&bufn[w][lane * 4] = o;
    __syncthreads();
    float px = (bufx[0][tid] + bufx[1][tid] + bufx[2][tid] + bufx[3][tid]) * 0.25f;
    float pn = (bufn[0][tid] + bufn[1][tid] + bufn[2][tid] + bufn[3][tid]) * 0.25f;
    poolx[(size_t)blk * 256 + tid] = px;
    Ppk[pk_idx(tid, blk)] = f2bf(pn);
}

// ---------------- packed-fragment MFMA GEMM: out = act(A @ W + bias) ----------------
template <int ACT>
__global__ __launch_bounds__(256) void gemm_pk_k(
    const ushortT* __restrict__ Apk,
    const ushortT* __restrict__ Bpk0, const float* __restrict__ b0, float* __restrict__ out0,
    const ushortT* __restrict__ Bpk1, const float* __restrict__ b1, float* __restrict__ out1)
{
    const ushortT* Bpk = blockIdx.z ? Bpk1 : Bpk0;
    const float* bias = blockIdx.z ? b1 : b0;
    float* out = blockIdx.z ? out1 : out0;
    int tid = threadIdx.x;
    int w = tid >> 6, l = tid & 63;
    int mt = blockIdx.x * 4 + w;        // 64-row tile index
    int n16b = blockIdx.y * 4;          // base 16-col tile index

    f32x4 acc[4][4];
    #pragma unroll
    for (int i = 0; i < 4; i++)
        #pragma unroll
        for (int j = 0; j < 4; j++) acc[i][j] = (f32x4){0.f, 0.f, 0.f, 0.f};

    #pragma unroll
    for (int kk = 0; kk < 8; kk++) {
        bf16x8 a[4], b[4];
        #pragma unroll
        for (int i = 0; i < 4; i++)
            a[i] = *(const bf16x8*)&Apk[((((size_t)(mt * 4 + i)) * 8 + kk) * 64 + l) * 8];
        #pragma unroll
        for (int j = 0; j < 4; j++)
            b[j] = *(const bf16x8*)&Bpk[((((size_t)(n16b + j)) * 8 + kk) * 64 + l) * 8];
        #pragma unroll
        for (int i = 0; i < 4; i++)
            #pragma unroll
            for (int j = 0; j < 4; j++)
                acc[i][j] = __builtin_amdgcn_mfma_f32_16x16x32_bf16(a[i], b[j], acc[i][j], 0, 0, 0);
    }

    int cr = l & 15, rg = l >> 4;
    float bs[4];
    #pragma unroll
    for (int j = 0; j < 4; j++) bs[j] = bias[(n16b + j) * 16 + cr];
    #pragma unroll
    for (int i = 0; i < 4; i++) {
        #pragma unroll
        for (int j = 0; j < 4; j++) {
            #pragma unroll
            for (int r = 0; r < 4; r++) {
                int row = (mt * 4 + i) * 16 + rg * 4 + r;
                int col = (n16b + j) * 16 + cr;
                float v = acc[i][j][r] + bs[j];
                out[(size_t)row * 256 + col] = (ACT == 1) ? softplus_f(v) : silu_f(v);
            }
        }
    }
}

// ---------------- delta GEMM: delta = softplus(u @ Wd^T + dt_b) ----------------
// A: f32 row-major u (8192,256), converted to bf16 in-flight. B: Wd row-major bf16
// (256,256). Wave tile 64x128 (acc[4][8]). grid (32, 2, 2).
__global__ __launch_bounds__(256) void gemm_delta_k(
    const float* __restrict__ u_f, const float* __restrict__ u_b,
    const ushortT* __restrict__ Wd_f, const ushortT* __restrict__ Wd_b,
    const float* __restrict__ dtb_f, const float* __restrict__ dtb_b,
    float* __restrict__ delta_f, float* __restrict__ delta_b)
{
    int dir = blockIdx.z;
    const float* U = dir ? u_b : u_f;
    const ushortT* W = dir ? Wd_b : Wd_f;
    const float* TB = dir ? dtb_b : dtb_f;
    float* OUT = dir ? delta_b : delta_f;
    int tid = threadIdx.x;
    int w = tid >> 6, l = tid & 63;
    int mt = blockIdx.x * 4 + w;        // 64-row tile
    int n16b = blockIdx.y * 8;          // base 16-col tile (covers 128 cols)
    int lr = l & 15, g = l >> 4;

    f32x4 acc[4][8];
    #pragma unroll
    for (int i = 0; i < 4; i++)
        #pragma unroll
        for (int j = 0; j < 8; j++) acc[i][j] = (f32x4){0.f, 0.f, 0.f, 0.f};

    #pragma unroll
    for (int kk = 0; kk < 8; kk++) {
        int k0 = kk * 32 + g * 8;
        bf16x8 a[4], b[8];
        #pragma unroll
        for (int i = 0; i < 4; i++) {
            const float* p = &U[(size_t)((mt * 4 + i) * 16 + lr) * 256 + k0];
            float4 v0 = *(const float4*)p;
            float4 v1 = *(const float4*)(p + 4);
            a[i] = cvt8(v0, v1);
        }
        #pragma unroll
        for (int j = 0; j < 8; j++)
            b[j] = *(const bf16x8*)&W[(size_t)((n16b + j) * 16 + lr) * 256 + k0];
        #pragma unroll
        for (int i = 0; i < 4; i++)
            #pragma unroll
            for (int j = 0; j < 8; j++)
                acc[i][j] = __builtin_amdgcn_mfma_f32_16x16x32_bf16(a[i], b[j], acc[i][j], 0, 0, 0);
    }

    int cr = l & 15, rg = l >> 4;
    #pragma unroll
    for (int j = 0; j < 8; j++) {
        float bs = TB[(n16b + j) * 16 + cr];
        #pragma unroll
        for (int i = 0; i < 4; i++) {
            #pragma unroll
            for (int r = 0; r < 4; r++) {
                int row = (mt * 4 + i) * 16 + rg * 4 + r;
                int col = (n16b + j) * 16 + cr;
                OUT[(size_t)row * 256 + col] = softplus_f(acc[i][j][r] + bs);
            }
        }
    }
}

// ---------------- BC GEMM: [B|C] = u @ Wbc^T ----------------
// A: f32 u. B: Wbc row-major bf16 (32,256). Wave tile 64x32 (acc[4][2]). grid (32,1,2).
__global__ __launch_bounds__(256) void gemm_bc_k(
    const float* __restrict__ u_f, const float* __restrict__ u_b,
    const ushortT* __restrict__ Wbc_f, const ushortT* __restrict__ Wbc_b,
    float* __restrict__ Bf, float* __restrict__ Cf,
    float* __restrict__ Bb, float* __restrict__ Cb)
{
    int dir = blockIdx.z;
    const float* U = dir ? u_b : u_f;
    const ushortT* W = dir ? Wbc_b : Wbc_f;
    float* BOUT = dir ? Bb : Bf;
    float* COUT = dir ? Cb : Cf;
    int tid = threadIdx.x;
    int w = tid >> 6, l = tid & 63;
    int mt = blockIdx.x * 4 + w;
    int lr = l & 15, g = l >> 4;

    f32x4 acc[4][2];
    #pragma unroll
    for (int i = 0; i < 4; i++)
        #pragma unroll
        for (int j = 0; j < 2; j++) acc[i][j] = (f32x4){0.f, 0.f, 0.f, 0.f};

    #pragma unroll
    for (int kk = 0; kk < 8; kk++) {
        int k0 = kk * 32 + g * 8;
        bf16x8 a[4], b[2];
        #pragma unroll
        for (int i = 0; i < 4; i++) {
            const float* p = &U[(size_t)((mt * 4 + i) * 16 + lr) * 256 + k0];
            float4 v0 = *(const float4*)p;
            float4 v1 = *(const float4*)(p + 4);
            a[i] = cvt8(v0, v1);
        }
        #pragma unroll
        for (int j = 0; j < 2; j++)
            b[j] = *(const bf16x8*)&W[(size_t)(j * 16 + lr) * 256 + k0];
        #pragma unroll
        for (int i = 0; i < 4; i++)
            #pragma unroll
            for (int j = 0; j < 2; j++)
                acc[i][j] = __builtin_amdgcn_mfma_f32_16x16x32_bf16(a[i], b[j], acc[i][j], 0, 0, 0);
    }

    int cr = l & 15, rg = l >> 4;
    #pragma unroll
    for (int i = 0; i < 4; i++) {
        #pragma unroll
        for (int r = 0; r < 4; r++) {
            int row = (mt * 4 + i) * 16 + rg * 4 + r;
            BOUT[(size_t)row * 16 + cr] = acc[i][0][r];
            COUT[(size_t)row * 16 + cr] = acc[i][1][r];
        }
    }
}

// ---------------- scan phase A: per-chunk (prod dA, h_out | h_in = 0) ----------------
__global__ __launch_bounds__(256) void scan_phaseA_k(
    const float* __restrict__ delta_f, const float* __restrict__ delta_b,
    const float* __restrict__ u_f, const float* __restrict__ u_b,
    const float* __restrict__ Bf, const float* __restrict__ Bb,
    const float* __restrict__ alog_f, const float* __restrict__ alog_b,
    float* __restrict__ hout, float* __restrict__ Pout)
{
    int chunk = blockIdx.x;   // 0..15
    int dblk = blockIdx.y;    // 0..15
    int z = blockIdx.z;       // dir*8 + b
    int dir = z >> 3, b = z & 7;
    int tid = threadIdx.x;
    int w = tid >> 6, lane = tid & 63;
    int g = lane >> 4, n = lane & 15;
    int d = dblk * 16 + w * 4 + g;

    const float* DELTA = dir ? delta_b : delta_f;
    const float* U = dir ? u_b : u_f;
    const float* Bm = dir ? Bb : Bf;
    const float* AL = dir ? alog_b : alog_f;

    float a_coef = -expf(AL[d * 16 + n]);

    int s0 = chunk * 64;
    int l0 = dir ? (1023 - s0) : s0;
    int lstep = dir ? -1 : 1;
    int base = b * 1024 + l0;
    const float* pd = DELTA + (size_t)base * 256 + d;
    const float* pu = U + (size_t)base * 256 + d;
    const float* pb = Bm + (size_t)base * 16 + n;
    int sd = lstep * 256, sb = lstep * 16;

    float h = 0.0f, P = 1.0f;
    #pragma unroll 4
    for (int j = 0; j < 64; j++) {
        float dlt = *pd;
        float uu = *pu;
        float bv = *pb;
        float dA = __expf(dlt * a_coef);
        h = dA * h + dlt * uu * bv;
        P *= dA;
        pd += sd; pu += sd; pb += sb;
    }
    int idx = ((z * 16 + chunk) * 256 + d) * 16 + n;
    hout[idx] = h;
    Pout[idx] = P;
}

// ---------------- scan phase B: sequential chunk combine ----------------
__global__ __launch_bounds__(256) void scan_phaseB_k(
    const float* __restrict__ hout, const float* __restrict__ Pout, float* __restrict__ hin)
{
    int gid = blockIdx.x * 256 + threadIdx.x;   // 65536
    int dn = gid & 4095;                        // d*16+n
    int z = gid >> 12;
    float h = 0.0f;
    #pragma unroll 4
    for (int c = 0; c < 16; c++) {
        int idx = (z * 16 + c) * 4096 + dn;
        hin[idx] = h;
        h = Pout[idx] * h + hout[idx];
    }
}

// ---------------- scan phase C: replay with correct h_in, pooled output ----------------
__global__ __launch_bounds__(256) void scan_phaseC_k(
    const float* __restrict__ delta_f, const float* __restrict__ delta_b,
    const float* __restrict__ u_f, const float* __restrict__ u_b,
    const float* __restrict__ Bf, const float* __restrict__ Bb,
    const float* __restrict__ Cf, const float* __restrict__ Cb,
    const float* __restrict__ alog_f, const float* __restrict__ alog_b,
    const float* __restrict__ Df, const float* __restrict__ Db,
    const float* __restrict__ hin,
    float* __restrict__ y1p, float* __restrict__ y2p)
{
    int chunk = blockIdx.x;
    int dblk = blockIdx.y;
    int z = blockIdx.z;
    int dir = z >> 3, b = z & 7;
    int tid = threadIdx.x;
    int w = tid >> 6, lane = tid & 63;
    int g = lane >> 4, n = lane & 15;
    int d = dblk * 16 + w * 4 + g;

    const float* DELTA = dir ? delta_b : delta_f;
    const float* U = dir ? u_b : u_f;
    const float* Bm = dir ? Bb : Bf;
    const float* Cm = dir ? Cb : Cf;
    const float* AL = dir ? alog_b : alog_f;
    const float* DD = dir ? Db : Df;
    float* YP = dir ? y2p : y1p;

    float a_coef = -expf(AL[d * 16 + n]);
    float Dd = DD[d];

    int s0 = chunk * 64;
    int l0 = dir ? (1023 - s0) : s0;
    int lstep = dir ? -1 : 1;
    int base = b * 1024 + l0;
    const float* pd = DELTA + (size_t)base * 256 + d;
    const float* pu = U + (size_t)base * 256 + d;
    const float* pb = Bm + (size_t)base * 16 + n;
    const float* pc = Cm + (size_t)base * 16 + n;
    int sd = lstep * 256, sb = lstep * 16;

    int idx = ((z * 16 + chunk) * 256 + d) * 16 + n;
    float h = hin[idx];

    for (int jb = 0; jb < 16; jb++) {
        float p = 0.0f, su = 0.0f;
        #pragma unroll
        for (int q = 0; q < 4; q++) {
            float dlt = *pd;
            float uu = *pu;
            float bv = *pb;
            float cv = *pc;
            float dA = __expf(dlt * a_coef);
            h = dA * h + dlt * uu * bv;
            p += h * cv;
            su += uu;
            pd += sd; pu += sd; pb += sb; pc += sb;
        }
        p += __shfl_xor(p, 1);
        p += __shfl_xor(p, 2);
        p += __shfl_xor(p, 4);
        p += __shfl_xor(p, 8);
        int l_last = l0 + lstep * (jb * 4 + 3);
        int t = l_last >> 2;
        if (n == 0) {
            YP[((size_t)(b * 256 + t)) * 256 + d] = (p + Dd * su) * 0.25f;
        }
    }
}

// ---------------- final: out = zp*(silu(y1p*mask)+silu(y2p*mask)) + skip ----------------
__global__ __launch_bounds__(256) void final_k(
    const float* __restrict__ zp, const float* __restrict__ y1p, const float* __restrict__ y2p,
    const float* __restrict__ poolx, const float* __restrict__ mask, float* __restrict__ out)
{
    int blk = blockIdx.x;
    int tid = threadIdx.x;
    int t = blk & 255;
    float m = mask[t];
    size_t idx = (size_t)blk * 256 + tid;
    float a = y1p[idx] * m;
    float c = y2p[idx] * m;
    out[idx] = zp[idx] * (silu_f(a) + silu_f(c)) + poolx[idx];
}

// ---------------- launcher ----------------
extern "C" void kernel_launch(void* const* d_in, const int* in_sizes, int n_in,
                              void* d_out, int out_size, void* d_ws, size_t ws_size,
                              hipStream_t stream)
{
    const float* x     = (const float*)d_in[0];
    const float* ln_g  = (const float*)d_in[1];
    const float* ln_b  = (const float*)d_in[2];
    const float* p1_w  = (const float*)d_in[3];
    const float* p1_b  = (const float*)d_in[4];
    const float* p2_w  = (const float*)d_in[5];
    const float* p2_b  = (const float*)d_in[6];
    const float* cf_w  = (const float*)d_in[7];
    const float* cf_b  = (const float*)d_in[8];
    const float* cb_w  = (const float*)d_in[9];
    const float* cb_b  = (const float*)d_in[10];
    const float* f_dbc = (const float*)d_in[11];
    const float* f_dtw = (const float*)d_in[12];
    const float* f_dtb = (const float*)d_in[13];
    const float* f_al  = (const float*)d_in[14];
    const float* f_D   = (const float*)d_in[15];
    const float* b_dbc = (const float*)d_in[16];
    const float* b_dtw = (const float*)d_in[17];
    const float* b_dtb = (const float*)d_in[18];
    const float* b_al  = (const float*)d_in[19];
    const float* b_D   = (const float*)d_in[20];

    float* ws = (float*)d_ws;
    float* u_f    = ws + OFF_UF;
    float* u_b    = ws + OFF_UB;
    float* delta_f= ws + OFF_DF;
    float* delta_b= ws + OFF_DB;
    float* Bf     = ws + OFF_BFa;
    float* Cf     = ws + OFF_CFa;
    float* Bb     = ws + OFF_BBa;
    float* Cb     = ws + OFF_CBa;
    float* poolx  = ws + OFF_POOLX;
    float* zp     = ws + OFF_ZP;
    float* y1p    = ws + OFF_Y1P;
    float* y2p    = ws + OFF_Y2P;
    float* bfb    = ws + OFF_BFB;
    float* bbb    = ws + OFF_BBB;
    float* maskw  = ws + OFF_MASK;
    float* hout   = ws + OFF_HOUT;
    float* Pprod  = ws + OFF_PPROD;
    float* hin    = ws + OFF_HIN;
    ushortT* Apk  = (ushortT*)(ws + OFF_APK);
    ushortT* Ppk  = (ushortT*)(ws + OFF_PPK);
    ushortT* Wfpk = (ushortT*)(ws + OFF_WFPK);
    ushortT* Wbpk = (ushortT*)(ws + OFF_WBPK);
    ushortT* P1pk = (ushortT*)(ws + OFF_P1PK);
    ushortT* Wd_f = (ushortT*)(ws + OFF_WD_F);
    ushortT* Wd_b = (ushortT*)(ws + OFF_WD_B);
    ushortT* Wbc_f= (ushortT*)(ws + OFF_WBC_F);
    ushortT* Wbc_b= (ushortT*)(ws + OFF_WBC_B);

    float* out = (float*)d_out;

    combine_w_k<<<dim3(256, 2), 256, 0, stream>>>(cf_w, cf_b, cb_w, cb_b, p2_w, p2_b,
                                                  Wfpk, bfb, Wbpk, bbb);
    pack_p1_k<<<256, 256, 0, stream>>>(p1_w, P1pk);
    wd_prep_k<<<dim3(288, 2), 256, 0, stream>>>(f_dbc, f_dtw, b_dbc, b_dtw,
                                                Wd_f, Wbc_f, Wd_b, Wbc_b);
    mask_k<<<1, 256, 0, stream>>>(maskw);
    ln_pool_k<<<2048, 256, 0, stream>>>(x, ln_g, ln_b, Apk, poolx, Ppk);
    gemm_pk_k<1><<<dim3(32, 4, 2), 256, 0, stream>>>(Apk, Wfpk, bfb, u_f, Wbpk, bbb, u_b);
    gemm_pk_k<2><<<dim3(8, 4, 1), 256, 0, stream>>>(Ppk, P1pk, p1_b, zp, P1pk, p1_b, zp);
    gemm_delta_k<<<dim3(32, 2, 2), 256, 0, stream>>>(u_f, u_b, Wd_f, Wd_b,
                                                     f_dtb, b_dtb, delta_f, delta_b);
    gemm_bc_k<<<dim3(32, 1, 2), 256, 0, stream>>>(u_f, u_b, Wbc_f, Wbc_b,
                                                  Bf, Cf, Bb, Cb);
    scan_phaseA_k<<<dim3(16, 16, 16), 256, 0, stream>>>(delta_f, delta_b, u_f, u_b,
                                                        Bf, Bb, f_al, b_al, hout, Pprod);
    scan_phaseB_k<<<256, 256, 0, stream>>>(hout, Pprod, hin);
    scan_phaseC_k<<<dim3(16, 16, 16), 256, 0, stream>>>(delta_f, delta_b, u_f, u_b,
                                                        Bf, Bb, Cf, Cb, f_al, b_al,
                                                        f_D, b_D, hin, y1p, y2p);
    final_k<<<2048, 256, 0, stream>>>(zp, y1p, y2p, poolx, maskw, out);
}

// Round 4
// 161.132 us; speedup vs baseline: 1.1969x; 1.1969x over previous
//
#include <hip/hip_runtime.h>
#include <hip/hip_bf16.h>
#include <math.h>

// ---------------- problem constants ----------------
#define SEQL 1024
#define DIMC 256
#define NBATCH 8
#define NTOK 256
#define NST 16

typedef unsigned short ushortT;
typedef unsigned int uintT;
using bf16x8 = __attribute__((ext_vector_type(8))) short;
using f32x4  = __attribute__((ext_vector_type(4))) float;

// ---------------- ws layout (float offsets) ----------------
static const size_t OFF_UF     = 0;            // 2097152 f32
static const size_t OFF_UB     = 2097152;      // 2097152
static const size_t OFF_DF     = 4194304;      // 2097152
static const size_t OFF_DB     = 6291456;      // 2097152
static const size_t OFF_BFa    = 8388608;      // 131072
static const size_t OFF_CFa    = 8519680;      // 131072
static const size_t OFF_BBa    = 8650752;      // 131072
static const size_t OFF_CBa    = 8781824;      // 131072
static const size_t OFF_POOLX  = 8912896;      // 524288
static const size_t OFF_ZP     = 9437184;      // 524288
static const size_t OFF_Y1P    = 9961472;      // 524288
static const size_t OFF_Y2P    = 10485760;     // 524288
static const size_t OFF_BFB    = 11010048;     // 256
static const size_t OFF_BBB    = 11010304;     // 256
static const size_t OFF_MASK   = 11010560;     // 256
static const size_t OFF_HOUT   = 11010816;     // 1048576
static const size_t OFF_PPROD  = 12059392;     // 1048576
static const size_t OFF_HIN    = 13107968;     // 1048576
// packed bf16 regions (sizes in f32 slots; 2 ushorts per slot)
static const size_t OFF_APK    = 14156544;     // 1048576 (Apk; reused as Upk_f after gemm_pk<1>)
static const size_t OFF_PPK    = 15205120;     // 262144
static const size_t OFF_WFPK   = 15467264;     // 32768
static const size_t OFF_WBPK   = 15500032;     // 32768
static const size_t OFF_P1PK   = 15532800;     // 32768
static const size_t OFF_WD_F   = 15565568;     // 32768 (packed fragments)
static const size_t OFF_WD_B   = 15598336;     // 32768
static const size_t OFF_WBC_F  = 15631104;     // 4096 (packed fragments, 32 cols)
static const size_t OFF_WBC_B  = 15635200;     // 4096
static const size_t OFF_UPKB   = 15639296;     // 1048576 (Upk_b)
// total 16687872 floats = ~66.8 MB (< 67.9 MB used in round 1)

__device__ __forceinline__ float softplus_f(float x) {
    return fmaxf(x, 0.0f) + log1pf(__expf(-fabsf(x)));
}
__device__ __forceinline__ float silu_f(float x) {
    return x / (1.0f + __expf(-x));
}
__device__ __forceinline__ ushortT f2bf(float f) {
    uintT u = __float_as_uint(f);
    uintT r = (u + 0x7FFFu + ((u >> 16) & 1u)) >> 16;
    return (ushortT)r;
}
// fragment-pack index for element (k, n): layout [n16][kk][lane][j],
// lane = g*16 + (n&15), k = kk*32 + g*8 + j
__device__ __forceinline__ size_t pk_idx(int k, int n) {
    int n16 = n >> 4, kk = k >> 5, g = (k >> 3) & 3, j = k & 7;
    return ((((size_t)n16 * 8 + kk) * 64) + g * 16 + (n & 15)) * 8 + j;
}

// ---------------- prep: combined conv∘p2 weights, packed bf16 ----------------
__global__ __launch_bounds__(256) void combine_w_k(
    const float* __restrict__ cf_w, const float* __restrict__ cf_b,
    const float* __restrict__ cb_w, const float* __restrict__ cb_b,
    const float* __restrict__ p2w, const float* __restrict__ p2b,
    ushortT* __restrict__ Wfpk, float* __restrict__ bf,
    ushortT* __restrict__ Wbpk, float* __restrict__ bb)
{
    int dir = blockIdx.y;
    const float* CW = dir ? cb_w : cf_w;
    const float* CB = dir ? cb_b : cf_b;
    ushortT* WPK = dir ? Wbpk : Wfpk;
    float* BO = dir ? bb : bf;
    int c = blockIdx.x;            // output channel -> GEMM col n
    int tid = threadIdx.x;         // input channel  -> GEMM k
    __shared__ float row[256];
    __shared__ float red[256];
    row[tid] = CW[c * 256 + tid];
    __syncthreads();
    float acc = 0.0f;
    for (int j = 0; j < 256; j++) acc += row[j] * p2w[j * 256 + tid];
    WPK[pk_idx(tid, c)] = f2bf(acc);
    red[tid] = row[tid] * p2b[tid];
    __syncthreads();
    for (int s = 128; s > 0; s >>= 1) {
        if (tid < s) red[tid] += red[tid + s];
        __syncthreads();
    }
    if (tid == 0) BO[c] = red[0] + CB[c];
}

__global__ __launch_bounds__(256) void pack_p1_k(const float* __restrict__ p1w,
                                                 ushortT* __restrict__ P1pk)
{
    int c = blockIdx.x, i = threadIdx.x;   // n = c, k = i
    P1pk[pk_idx(i, c)] = f2bf(p1w[c * 256 + i]);
}

// Wd[d][k] = sum_r dt_w[d][r] * dbc_w[r][k]  -> packed fragments (n = d, 256 cols)
// Wbc[rr][k] = dbc_w[16+rr][k]               -> packed fragments (n = rr, 32 cols)
__global__ __launch_bounds__(256) void wd_prep_k(
    const float* __restrict__ dbcw_f, const float* __restrict__ dtw_f,
    const float* __restrict__ dbcw_b, const float* __restrict__ dtw_b,
    ushortT* __restrict__ Wd_f, ushortT* __restrict__ Wbc_f,
    ushortT* __restrict__ Wd_b, ushortT* __restrict__ Wbc_b)
{
    int dir = blockIdx.y;
    const float* DW = dir ? dbcw_b : dbcw_f;
    const float* TW = dir ? dtw_b : dtw_f;
    int xr = blockIdx.x, k = threadIdx.x;
    if (xr < 256) {
        float acc = 0.0f;
        #pragma unroll
        for (int r = 0; r < 16; r++) acc += TW[xr * 16 + r] * DW[r * 256 + k];
        (dir ? Wd_b : Wd_f)[pk_idx(k, xr)] = f2bf(acc);
    } else {
        int rr = xr - 256;   // 0..31
        (dir ? Wbc_b : Wbc_f)[pk_idx(k, rr)] = f2bf(DW[(16 + rr) * 256 + k]);
    }
}

__global__ __launch_bounds__(256) void mask_k(float* __restrict__ mask)
{
    int t = threadIdx.x;
    float dx = (float)t - 128.0f;
    float wv = __expf(-0.5f * dx * dx / 4096.0f);   // sigma = 64 exactly
    __shared__ float red[256];
    red[t] = wv;
    __syncthreads();
    for (int s = 128; s > 0; s >>= 1) {
        if (t < s) red[t] += red[t + s];
        __syncthreads();
    }
    mask[t] = wv / red[0];
}

// ---------------- LayerNorm + adapool(x) + packed xn / packed pool(xn) ----------------
__global__ __launch_bounds__(256) void ln_pool_k(
    const float* __restrict__ x, const float* __restrict__ g, const float* __restrict__ be,
    ushortT* __restrict__ Apk, float* __restrict__ poolx, ushortT* __restrict__ Ppk)
{
    int blk = blockIdx.x;           // b*256 + t
    int tid = threadIdx.x;
    int w = tid >> 6, lane = tid & 63;
    __shared__ float bufx[4][256];
    __shared__ float bufn[4][256];
    int row = blk * 4 + w;          // = b*1024 + 4t + w
    float4 v = *(const float4*)&x[(size_t)row * 256 + lane * 4];
    float s = v.x + v.y + v.z + v.w;
    #pragma unroll
    for (int m = 1; m < 64; m <<= 1) s += __shfl_xor(s, m);
    float mu = s * (1.0f / 256.0f);
    float cx = v.x - mu, cy = v.y - mu, cz = v.z - mu, cw = v.w - mu;
    float ss = cx * cx + cy * cy + cz * cz + cw * cw;
    #pragma unroll
    for (int m = 1; m < 64; m <<= 1) ss += __shfl_xor(ss, m);
    float rs = rsqrtf(ss * (1.0f / 256.0f) + 1e-5f);
    float4 g4 = *(const float4*)&g[lane * 4];
    float4 b4 = *(const float4*)&be[lane * 4];
    float4 o;
    o.x = cx * rs * g4.x + b4.x;
    o.y = cy * rs * g4.y + b4.y;
    o.z = cz * rs * g4.z + b4.z;
    o.w = cw * rs * g4.w + b4.w;
    {
        int c0 = lane * 4;
        size_t pidx = pk_idx(c0, row);
        ushort4 pv;
        pv.x = f2bf(o.x); pv.y = f2bf(o.y); pv.z = f2bf(o.z); pv.w = f2bf(o.w);
        *(ushort4*)&Apk[pidx] = pv;
    }
    *(float4*)&bufx[w][lane * 4] = v;
    *(float4*)&bufn[w][lane * 4] = o;
    __syncthreads();
    float px = (bufx[0][tid] + bufx[1][tid] + bufx[2][tid] + bufx[3][tid]) * 0.25f;
    float pn = (bufn[0][tid] + bufn[1][tid] + bufn[2][tid] + bufn[3][tid]) * 0.25f;
    poolx[(size_t)blk * 256 + tid] = px;
    Ppk[pk_idx(tid, blk)] = f2bf(pn);
}

// ---------------- packed-fragment MFMA GEMM: out = act(A @ W + bias) ----------------
template <int ACT>
__global__ __launch_bounds__(256) void gemm_pk_k(
    const ushortT* __restrict__ Apk,
    const ushortT* __restrict__ Bpk0, const float* __restrict__ b0, float* __restrict__ out0,
    const ushortT* __restrict__ Bpk1, const float* __restrict__ b1, float* __restrict__ out1)
{
    const ushortT* Bpk = blockIdx.z ? Bpk1 : Bpk0;
    const float* bias = blockIdx.z ? b1 : b0;
    float* out = blockIdx.z ? out1 : out0;
    int tid = threadIdx.x;
    int w = tid >> 6, l = tid & 63;
    int mt = blockIdx.x * 4 + w;        // 64-row tile index
    int n16b = blockIdx.y * 4;          // base 16-col tile index

    f32x4 acc[4][4];
    #pragma unroll
    for (int i = 0; i < 4; i++)
        #pragma unroll
        for (int j = 0; j < 4; j++) acc[i][j] = (f32x4){0.f, 0.f, 0.f, 0.f};

    #pragma unroll
    for (int kk = 0; kk < 8; kk++) {
        bf16x8 a[4], b[4];
        #pragma unroll
        for (int i = 0; i < 4; i++)
            a[i] = *(const bf16x8*)&Apk[((((size_t)(mt * 4 + i)) * 8 + kk) * 64 + l) * 8];
        #pragma unroll
        for (int j = 0; j < 4; j++)
            b[j] = *(const bf16x8*)&Bpk[((((size_t)(n16b + j)) * 8 + kk) * 64 + l) * 8];
        #pragma unroll
        for (int i = 0; i < 4; i++)
            #pragma unroll
            for (int j = 0; j < 4; j++)
                acc[i][j] = __builtin_amdgcn_mfma_f32_16x16x32_bf16(a[i], b[j], acc[i][j], 0, 0, 0);
    }

    int cr = l & 15, rg = l >> 4;
    float bs[4];
    #pragma unroll
    for (int j = 0; j < 4; j++) bs[j] = bias[(n16b + j) * 16 + cr];
    #pragma unroll
    for (int i = 0; i < 4; i++) {
        #pragma unroll
        for (int j = 0; j < 4; j++) {
            #pragma unroll
            for (int r = 0; r < 4; r++) {
                int row = (mt * 4 + i) * 16 + rg * 4 + r;
                int col = (n16b + j) * 16 + cr;
                float v = acc[i][j][r] + bs[j];
                out[(size_t)row * 256 + col] = (ACT == 1) ? softplus_f(v) : silu_f(v);
            }
        }
    }
}

// ---------------- pack u f32 -> fragment-packed bf16 (LDS bounce) ----------------
__global__ __launch_bounds__(256) void pack_u_k(
    const float* __restrict__ u_f, const float* __restrict__ u_b,
    ushortT* __restrict__ Upk_f, ushortT* __restrict__ Upk_b)
{
    int dir = blockIdx.y;
    const float* U = dir ? u_b : u_f;
    ushortT* UPK = dir ? Upk_b : Upk_f;
    int m16 = blockIdx.x;            // 0..511 (16-row group)
    int tid = threadIdx.x;
    __shared__ ushortT lds[16 * 264];
    // stage 1: coalesced load of 16 rows x 256 cols, convert to bf16 in LDS
    #pragma unroll
    for (int i = 0; i < 4; i++) {
        int idx = tid + i * 256;     // 1024 float4 units
        int r = idx >> 6, c4 = idx & 63;
        float4 v = *(const float4*)&U[((size_t)m16 * 16 + r) * 256 + c4 * 4];
        ushort4 pv;
        pv.x = f2bf(v.x); pv.y = f2bf(v.y); pv.z = f2bf(v.z); pv.w = f2bf(v.w);
        *(ushort4*)&lds[r * 264 + c4 * 4] = pv;
    }
    __syncthreads();
    // stage 2: write packed fragments, coalesced 16B per lane-slot
    int kk = tid >> 5;
    int l0 = (tid & 31) * 2;
    size_t outbase = (((size_t)m16 * 8) + kk) * 512;   // [m16][kk][lane(64)][j(8)]
    #pragma unroll
    for (int q = 0; q < 2; q++) {
        int l = l0 + q;
        int g = l >> 4, mm = l & 15;
        const ushortT* src = &lds[mm * 264 + kk * 32 + g * 8];
        ushort4 a = *(const ushort4*)src;
        ushort4 b = *(const ushort4*)(src + 4);
        *(ushort4*)&UPK[outbase + (size_t)l * 8] = a;
        *(ushort4*)&UPK[outbase + (size_t)l * 8 + 4] = b;
    }
}

// ---------------- delta GEMM (packed): delta = softplus(Upk @ Wd^T + dt_b) ----------------
__global__ __launch_bounds__(256) void gemm_delta_pk_k(
    const ushortT* __restrict__ Upk_f, const ushortT* __restrict__ Upk_b,
    const ushortT* __restrict__ Wd_f, const ushortT* __restrict__ Wd_b,
    const float* __restrict__ dtb_f, const float* __restrict__ dtb_b,
    float* __restrict__ delta_f, float* __restrict__ delta_b)
{
    const ushortT* Apk = blockIdx.z ? Upk_b : Upk_f;
    const ushortT* Bpk = blockIdx.z ? Wd_b : Wd_f;
    const float* bias = blockIdx.z ? dtb_b : dtb_f;
    float* out = blockIdx.z ? delta_b : delta_f;
    int tid = threadIdx.x;
    int w = tid >> 6, l = tid & 63;
    int mt = blockIdx.x * 4 + w;
    int n16b = blockIdx.y * 4;

    f32x4 acc[4][4];
    #pragma unroll
    for (int i = 0; i < 4; i++)
        #pragma unroll
        for (int j = 0; j < 4; j++) acc[i][j] = (f32x4){0.f, 0.f, 0.f, 0.f};

    #pragma unroll
    for (int kk = 0; kk < 8; kk++) {
        bf16x8 a[4], b[4];
        #pragma unroll
        for (int i = 0; i < 4; i++)
            a[i] = *(const bf16x8*)&Apk[((((size_t)(mt * 4 + i)) * 8 + kk) * 64 + l) * 8];
        #pragma unroll
        for (int j = 0; j < 4; j++)
            b[j] = *(const bf16x8*)&Bpk[((((size_t)(n16b + j)) * 8 + kk) * 64 + l) * 8];
        #pragma unroll
        for (int i = 0; i < 4; i++)
            #pragma unroll
            for (int j = 0; j < 4; j++)
                acc[i][j] = __builtin_amdgcn_mfma_f32_16x16x32_bf16(a[i], b[j], acc[i][j], 0, 0, 0);
    }

    int cr = l & 15, rg = l >> 4;
    float bs[4];
    #pragma unroll
    for (int j = 0; j < 4; j++) bs[j] = bias[(n16b + j) * 16 + cr];
    #pragma unroll
    for (int i = 0; i < 4; i++) {
        #pragma unroll
        for (int j = 0; j < 4; j++) {
            #pragma unroll
            for (int r = 0; r < 4; r++) {
                int row = (mt * 4 + i) * 16 + rg * 4 + r;
                int col = (n16b + j) * 16 + cr;
                out[(size_t)row * 256 + col] = softplus_f(acc[i][j][r] + bs[j]);
            }
        }
    }
}

// ---------------- BC GEMM (packed): [B|C] = Upk @ Wbc^T ----------------
// grid (128, 2): each wave one 16-row tile x 32 cols.
__global__ __launch_bounds__(256) void gemm_bc_pk_k(
    const ushortT* __restrict__ Upk_f, const ushortT* __restrict__ Upk_b,
    const ushortT* __restrict__ Wbc_f, const ushortT* __restrict__ Wbc_b,
    float* __restrict__ Bf, float* __restrict__ Cf,
    float* __restrict__ Bb, float* __restrict__ Cb)
{
    int dir = blockIdx.y;
    const ushortT* Apk = dir ? Upk_b : Upk_f;
    const ushortT* Bpk = dir ? Wbc_b : Wbc_f;
    float* BOUT = dir ? Bb : Bf;
    float* COUT = dir ? Cb : Cf;
    int tid = threadIdx.x;
    int w = tid >> 6, l = tid & 63;
    int m16 = blockIdx.x * 4 + w;   // 0..511

    f32x4 acc[2];
    acc[0] = (f32x4){0.f, 0.f, 0.f, 0.f};
    acc[1] = (f32x4){0.f, 0.f, 0.f, 0.f};

    #pragma unroll
    for (int kk = 0; kk < 8; kk++) {
        bf16x8 a = *(const bf16x8*)&Apk[(((size_t)m16 * 8 + kk) * 64 + l) * 8];
        bf16x8 b0 = *(const bf16x8*)&Bpk[(((size_t)0 * 8 + kk) * 64 + l) * 8];
        bf16x8 b1 = *(const bf16x8*)&Bpk[(((size_t)1 * 8 + kk) * 64 + l) * 8];
        acc[0] = __builtin_amdgcn_mfma_f32_16x16x32_bf16(a, b0, acc[0], 0, 0, 0);
        acc[1] = __builtin_amdgcn_mfma_f32_16x16x32_bf16(a, b1, acc[1], 0, 0, 0);
    }

    int cr = l & 15, rg = l >> 4;
    #pragma unroll
    for (int r = 0; r < 4; r++) {
        int row = m16 * 16 + rg * 4 + r;
        BOUT[(size_t)row * 16 + cr] = acc[0][r];
        COUT[(size_t)row * 16 + cr] = acc[1][r];
    }
}

// ---------------- scan phase A: per-chunk (prod dA, h_out | h_in = 0) ----------------
__global__ __launch_bounds__(256) void scan_phaseA_k(
    const float* __restrict__ delta_f, const float* __restrict__ delta_b,
    const float* __restrict__ u_f, const float* __restrict__ u_b,
    const float* __restrict__ Bf, const float* __restrict__ Bb,
    const float* __restrict__ alog_f, const float* __restrict__ alog_b,
    float* __restrict__ hout, float* __restrict__ Pout)
{
    int chunk = blockIdx.x;   // 0..15
    int dblk = blockIdx.y;    // 0..15
    int z = blockIdx.z;       // dir*8 + b
    int dir = z >> 3, b = z & 7;
    int tid = threadIdx.x;
    int w = tid >> 6, lane = tid & 63;
    int g = lane >> 4, n = lane & 15;
    int d = dblk * 16 + w * 4 + g;

    const float* DELTA = dir ? delta_b : delta_f;
    const float* U = dir ? u_b : u_f;
    const float* Bm = dir ? Bb : Bf;
    const float* AL = dir ? alog_b : alog_f;

    float a_coef = -expf(AL[d * 16 + n]);

    int s0 = chunk * 64;
    int l0 = dir ? (1023 - s0) : s0;
    int lstep = dir ? -1 : 1;
    int base = b * 1024 + l0;
    const float* pd = DELTA + (size_t)base * 256 + d;
    const float* pu = U + (size_t)base * 256 + d;
    const float* pb = Bm + (size_t)base * 16 + n;
    int sd = lstep * 256, sb = lstep * 16;

    float h = 0.0f, P = 1.0f;
    #pragma unroll 4
    for (int j = 0; j < 64; j++) {
        float dlt = *pd;
        float uu = *pu;
        float bv = *pb;
        float dA = __expf(dlt * a_coef);
        h = dA * h + dlt * uu * bv;
        P *= dA;
        pd += sd; pu += sd; pb += sb;
    }
    int idx = ((z * 16 + chunk) * 256 + d) * 16 + n;
    hout[idx] = h;
    Pout[idx] = P;
}

// ---------------- scan phase B: sequential chunk combine ----------------
__global__ __launch_bounds__(256) void scan_phaseB_k(
    const float* __restrict__ hout, const float* __restrict__ Pout, float* __restrict__ hin)
{
    int gid = blockIdx.x * 256 + threadIdx.x;   // 65536
    int dn = gid & 4095;                        // d*16+n
    int z = gid >> 12;
    float h = 0.0f;
    #pragma unroll 4
    for (int c = 0; c < 16; c++) {
        int idx = (z * 16 + c) * 4096 + dn;
        hin[idx] = h;
        h = Pout[idx] * h + hout[idx];
    }
}

// ---------------- scan phase C: replay with correct h_in, pooled output ----------------
__global__ __launch_bounds__(256) void scan_phaseC_k(
    const float* __restrict__ delta_f, const float* __restrict__ delta_b,
    const float* __restrict__ u_f, const float* __restrict__ u_b,
    const float* __restrict__ Bf, const float* __restrict__ Bb,
    const float* __restrict__ Cf, const float* __restrict__ Cb,
    const float* __restrict__ alog_f, const float* __restrict__ alog_b,
    const float* __restrict__ Df, const float* __restrict__ Db,
    const float* __restrict__ hin,
    float* __restrict__ y1p, float* __restrict__ y2p)
{
    int chunk = blockIdx.x;
    int dblk = blockIdx.y;
    int z = blockIdx.z;
    int dir = z >> 3, b = z & 7;
    int tid = threadIdx.x;
    int w = tid >> 6, lane = tid & 63;
    int g = lane >> 4, n = lane & 15;
    int d = dblk * 16 + w * 4 + g;

    const float* DELTA = dir ? delta_b : delta_f;
    const float* U = dir ? u_b : u_f;
    const float* Bm = dir ? Bb : Bf;
    const float* Cm = dir ? Cb : Cf;
    const float* AL = dir ? alog_b : alog_f;
    const float* DD = dir ? Db : Df;
    float* YP = dir ? y2p : y1p;

    float a_coef = -expf(AL[d * 16 + n]);
    float Dd = DD[d];

    int s0 = chunk * 64;
    int l0 = dir ? (1023 - s0) : s0;
    int lstep = dir ? -1 : 1;
    int base = b * 1024 + l0;
    const float* pd = DELTA + (size_t)base * 256 + d;
    const float* pu = U + (size_t)base * 256 + d;
    const float* pb = Bm + (size_t)base * 16 + n;
    const float* pc = Cm + (size_t)base * 16 + n;
    int sd = lstep * 256, sb = lstep * 16;

    int idx = ((z * 16 + chunk) * 256 + d) * 16 + n;
    float h = hin[idx];

    for (int jb = 0; jb < 16; jb++) {
        float p = 0.0f, su = 0.0f;
        #pragma unroll
        for (int q = 0; q < 4; q++) {
            float dlt = *pd;
            float uu = *pu;
            float bv = *pb;
            float cv = *pc;
            float dA = __expf(dlt * a_coef);
            h = dA * h + dlt * uu * bv;
            p += h * cv;
            su += uu;
            pd += sd; pu += sd; pb += sb; pc += sb;
        }
        p += __shfl_xor(p, 1);
        p += __shfl_xor(p, 2);
        p += __shfl_xor(p, 4);
        p += __shfl_xor(p, 8);
        int l_last = l0 + lstep * (jb * 4 + 3);
        int t = l_last >> 2;
        if (n == 0) {
            YP[((size_t)(b * 256 + t)) * 256 + d] = (p + Dd * su) * 0.25f;
        }
    }
}

// ---------------- final: out = zp*(silu(y1p*mask)+silu(y2p*mask)) + skip ----------------
__global__ __launch_bounds__(256) void final_k(
    const float* __restrict__ zp, const float* __restrict__ y1p, const float* __restrict__ y2p,
    const float* __restrict__ poolx, const float* __restrict__ mask, float* __restrict__ out)
{
    int blk = blockIdx.x;
    int tid = threadIdx.x;
    int t = blk & 255;
    float m = mask[t];
    size_t idx = (size_t)blk * 256 + tid;
    float a = y1p[idx] * m;
    float c = y2p[idx] * m;
    out[idx] = zp[idx] * (silu_f(a) + silu_f(c)) + poolx[idx];
}

// ---------------- launcher ----------------
extern "C" void kernel_launch(void* const* d_in, const int* in_sizes, int n_in,
                              void* d_out, int out_size, void* d_ws, size_t ws_size,
                              hipStream_t stream)
{
    const float* x     = (const float*)d_in[0];
    const float* ln_g  = (const float*)d_in[1];
    const float* ln_b  = (const float*)d_in[2];
    const float* p1_w  = (const float*)d_in[3];
    const float* p1_b  = (const float*)d_in[4];
    const float* p2_w  = (const float*)d_in[5];
    const float* p2_b  = (const float*)d_in[6];
    const float* cf_w  = (const float*)d_in[7];
    const float* cf_b  = (const float*)d_in[8];
    const float* cb_w  = (const float*)d_in[9];
    const float* cb_b  = (const float*)d_in[10];
    const float* f_dbc = (const float*)d_in[11];
    const float* f_dtw = (const float*)d_in[12];
    const float* f_dtb = (const float*)d_in[13];
    const float* f_al  = (const float*)d_in[14];
    const float* f_D   = (const float*)d_in[15];
    const float* b_dbc = (const float*)d_in[16];
    const float* b_dtw = (const float*)d_in[17];
    const float* b_dtb = (const float*)d_in[18];
    const float* b_al  = (const float*)d_in[19];
    const float* b_D   = (const float*)d_in[20];

    float* ws = (float*)d_ws;
    float* u_f    = ws + OFF_UF;
    float* u_b    = ws + OFF_UB;
    float* delta_f= ws + OFF_DF;
    float* delta_b= ws + OFF_DB;
    float* Bf     = ws + OFF_BFa;
    float* Cf     = ws + OFF_CFa;
    float* Bb     = ws + OFF_BBa;
    float* Cb     = ws + OFF_CBa;
    float* poolx  = ws + OFF_POOLX;
    float* zp     = ws + OFF_ZP;
    float* y1p    = ws + OFF_Y1P;
    float* y2p    = ws + OFF_Y2P;
    float* bfb    = ws + OFF_BFB;
    float* bbb    = ws + OFF_BBB;
    float* maskw  = ws + OFF_MASK;
    float* hout   = ws + OFF_HOUT;
    float* Pprod  = ws + OFF_PPROD;
    float* hin    = ws + OFF_HIN;
    ushortT* Apk  = (ushortT*)(ws + OFF_APK);
    ushortT* Ppk  = (ushortT*)(ws + OFF_PPK);
    ushortT* Wfpk = (ushortT*)(ws + OFF_WFPK);
    ushortT* Wbpk = (ushortT*)(ws + OFF_WBPK);
    ushortT* P1pk = (ushortT*)(ws + OFF_P1PK);
    ushortT* Wd_f = (ushortT*)(ws + OFF_WD_F);
    ushortT* Wd_b = (ushortT*)(ws + OFF_WD_B);
    ushortT* Wbc_f= (ushortT*)(ws + OFF_WBC_F);
    ushortT* Wbc_b= (ushortT*)(ws + OFF_WBC_B);
    ushortT* Upk_f= (ushortT*)(ws + OFF_APK);    // reuse Apk region (dead after gemm_pk<1>)
    ushortT* Upk_b= (ushortT*)(ws + OFF_UPKB);

    float* out = (float*)d_out;

    combine_w_k<<<dim3(256, 2), 256, 0, stream>>>(cf_w, cf_b, cb_w, cb_b, p2_w, p2_b,
                                                  Wfpk, bfb, Wbpk, bbb);
    pack_p1_k<<<256, 256, 0, stream>>>(p1_w, P1pk);
    wd_prep_k<<<dim3(288, 2), 256, 0, stream>>>(f_dbc, f_dtw, b_dbc, b_dtw,
                                                Wd_f, Wbc_f, Wd_b, Wbc_b);
    mask_k<<<1, 256, 0, stream>>>(maskw);
    ln_pool_k<<<2048, 256, 0, stream>>>(x, ln_g, ln_b, Apk, poolx, Ppk);
    gemm_pk_k<1><<<dim3(32, 4, 2), 256, 0, stream>>>(Apk, Wfpk, bfb, u_f, Wbpk, bbb, u_b);
    gemm_pk_k<2><<<dim3(8, 4, 1), 256, 0, stream>>>(Ppk, P1pk, p1_b, zp, P1pk, p1_b, zp);
    pack_u_k<<<dim3(512, 2), 256, 0, stream>>>(u_f, u_b, Upk_f, Upk_b);
    gemm_delta_pk_k<<<dim3(32, 4, 2), 256, 0, stream>>>(Upk_f, Upk_b, Wd_f, Wd_b,
                                                        f_dtb, b_dtb, delta_f, delta_b);
    gemm_bc_pk_k<<<dim3(128, 2), 256, 0, stream>>>(Upk_f, Upk_b, Wbc_f, Wbc_b,
                                                   Bf, Cf, Bb, Cb);
    scan_phaseA_k<<<dim3(16, 16, 16), 256, 0, stream>>>(delta_f, delta_b, u_f, u_b,
                                                        Bf, Bb, f_al, b_al, hout, Pprod);
    scan_phaseB_k<<<256, 256, 0, stream>>>(hout, Pprod, hin);
    scan_phaseC_k<<<dim3(16, 16, 16), 256, 0, stream>>>(delta_f, delta_b, u_f, u_b,
                                                        Bf, Bb, Cf, Cb, f_al, b_al,
                                                        f_D, b_D, hin, y1p, y2p);
    final_k<<<2048, 256, 0, stream>>>(zp, y1p, y2p, poolx, maskw, out);
}